// Round 1
// baseline (21797.369 us; speedup 1.0000x reference)
//
#include <hip/hip_runtime.h>
#include <math.h>

// ---------------------------------------------------------------------------
// FISTA sparse solver, L=128, D=512, M=2048, MAX_ITER=200, EPS=1e-5.
// Design:
//  - ~440 kernels enqueued per launch; per-iteration K1 (grad+prox, conv check)
//    and K2 (A_new@x, R, hankel-tail partials). Device-side `done` flag gives
//    the reference's early exit inside a captured graph.
//  - A/Bm double-buffered by iteration parity; K1 writes speculatively so the
//    pre-update state survives when convergence triggers.
//  - max eig of x x^T: 16 normalized squarings + 4 power matvecs + fp64
//    matrix-free Rayleigh (two passes through x). Delta^T Delta: 14 squarings.
//  - All reductions fixed-order (deterministic across graph replays).
// ---------------------------------------------------------------------------

#define L 128
#define D 512
#define M 2048
#define NY (L + M - 1)   // 2175
#define TAIL (L - 1)     // 127
#define MAXIT 200
#define EPSV 1e-5f
#define LAM1 0.1f
#define LAM2C 0.1f

// workspace offsets (in floats)
#define OFF_A     0           // 2 x (L*D)
#define OFF_BM    131072      // 2 x (L*D)
#define OFF_R     262144      // L*M
#define OFF_AX    524288      // L*M
#define OFF_P     786432      // 512x512
#define OFF_Q     1048576     // 512x512
#define OFF_DTD   1310720     // 128x128
#define OFF_DP    1327104     // 128x128
#define OFF_DQ    1343488     // 128x128
#define OFF_CTAB  1359872     // 256
#define OFF_YPREV 1360128     // 128
#define OFF_PART  1360256     // 16 x 128
#define OFF_WV    1362304     // 512
#define OFF_VV    1362816     // 512
#define OFF_T64   1363328     // 2048 doubles (4096 floats)
#define OFF_Y64   1367424     // 512 doubles (1024 floats)
#define OFF_SCAL  1368448     // 64
#define OFF_WD    1368512     // 128
#define OFF_WD2   1368640     // 128
// total: 1368768 floats = ~5.23 MiB (<< typical ws_size)

// scalar slots (float index relative to OFF_SCAL)
#define SC_MX    0    // 0..16  squaring maxima (x chain)
#define SC_MXD   24   // 24..38 squaring maxima (delta chain)
#define SC_EIGD  44
#define SC_TAU   45
#define SC_THR   46
// int slots (int view of same region)
#define SI_DONE  48
#define SI_PAR   49

__device__ __forceinline__ float delta_elem(int i, int j) {
  if (i == 0) return 0.f;
  if (i == 1) return (j == 0) ? -1.f : (j == 1 ? 1.f : 0.f);
  return (j == i) ? 1.f : (j == i - 1 ? -2.f : (j == i - 2 ? 1.f : 0.f));
}

// ---------------- init: zero state, R0, DtD, ctab, yprev, scalars ----------
__global__ __launch_bounds__(256) void k_init(float* __restrict__ ws,
                                              const float* __restrict__ part_y,
                                              const float* __restrict__ mask,
                                              const float* __restrict__ y0) {
  int gid = blockIdx.x * blockDim.x + threadIdx.x;
  int stride = gridDim.x * blockDim.x;
  // zero A[2], Bm[2] (contiguous 262144 floats)
  for (int i = gid; i < 4 * L * D; i += stride) ws[OFF_A + i] = 0.f;
  // R0 = mask * (0 - part_y)
  for (int i = gid; i < L * M; i += stride) ws[OFF_R + i] = -mask[i] * part_y[i];
  // DtD = Delta^T Delta
  for (int i = gid; i < L * L; i += stride) {
    int r = i / L, c = i % L;
    float s = 0.f;
    for (int k = 0; k < L; ++k) s += delta_elem(k, r) * delta_elem(k, c);
    ws[OFF_DTD + i] = s;
  }
  if (gid < TAIL) ws[OFF_YPREV + gid] = y0[M + gid];  // last 127 of y0
  if (gid == 0) {
    for (int i = 0; i < 64; ++i) ws[OFF_SCAL + i] = 0.f;  // also zeroes done/parity
    ws[OFF_SCAL + SC_MXD] = 6.0f;  // exact max|DtD| (interior diagonal 1+4+1)
    float a = 1.f;
    for (int t = 0; t < MAXIT; ++t) {
      float an = (1.f + sqrtf(1.f + 4.f * a * a)) * 0.5f;
      ws[OFF_CTAB + t] = (a - 1.f) / an;
      a = an;
    }
  }
}

// ---------------- B = x x^T (512x512), track max|entry| --------------------
__global__ __launch_bounds__(256) void k_xxt(const float* __restrict__ x,
                                             float* __restrict__ ws) {
  int bt = blockIdx.x;                       // 256 blocks: 16x16 tiles of 32x32
  int r0 = (bt / 16) * 32, c0 = (bt % 16) * 32;
  int rr = threadIdx.x / 32, cl = threadIdx.x % 32;
  int c = c0 + cl;
  const float4* xc = (const float4*)(x + (size_t)c * M);
  float acc[4] = {0.f, 0.f, 0.f, 0.f};
  for (int m4 = 0; m4 < M / 4; ++m4) {
    float4 b = xc[m4];
#pragma unroll
    for (int k = 0; k < 4; ++k) {
      float4 a = ((const float4*)(x + (size_t)(r0 + rr + 8 * k) * M))[m4];
      acc[k] += a.x * b.x + a.y * b.y + a.z * b.z + a.w * b.w;
    }
  }
  float* P = ws + OFF_P;
  float mloc = 0.f;
#pragma unroll
  for (int k = 0; k < 4; ++k) {
    P[(size_t)(r0 + rr + 8 * k) * D + c] = acc[k];
    mloc = fmaxf(mloc, fabsf(acc[k]));
  }
  __shared__ float sm[256];
  sm[threadIdx.x] = mloc; __syncthreads();
  for (int s = 128; s > 0; s >>= 1) {
    if ((int)threadIdx.x < s) sm[threadIdx.x] = fmaxf(sm[threadIdx.x], sm[threadIdx.x + s]);
    __syncthreads();
  }
  if (threadIdx.x == 0) atomicMax((int*)(ws + OFF_SCAL + SC_MX), __float_as_int(sm[0]));
}

// ---------------- symmetric matrix squaring: dst = (src/m)^2 ---------------
template <int N, int TILES>
__global__ __launch_bounds__(256) void k_sq(const float* __restrict__ src,
                                            float* __restrict__ dst,
                                            float* __restrict__ ws,
                                            int slotIn, int slotOut) {
  float sc = 1.0f / ws[OFF_SCAL + slotIn];
  int bt = blockIdx.x;
  int r0 = (bt / TILES) * 32, c0 = (bt % TILES) * 32;
  int rr = threadIdx.x / 32, cl = threadIdx.x % 32;
  int c = c0 + cl;
  const float4* bc = (const float4*)(src + (size_t)c * N);  // symmetric: row c
  float acc[4] = {0.f, 0.f, 0.f, 0.f};
  for (int m4 = 0; m4 < N / 4; ++m4) {
    float4 b = bc[m4];
#pragma unroll
    for (int k = 0; k < 4; ++k) {
      float4 a = ((const float4*)(src + (size_t)(r0 + rr + 8 * k) * N))[m4];
      acc[k] += a.x * b.x + a.y * b.y + a.z * b.z + a.w * b.w;
    }
  }
  float mloc = 0.f;
#pragma unroll
  for (int k = 0; k < 4; ++k) {
    float v = acc[k] * sc * sc;
    dst[(size_t)(r0 + rr + 8 * k) * N + c] = v;
    mloc = fmaxf(mloc, fabsf(v));
  }
  __shared__ float sm[256];
  sm[threadIdx.x] = mloc; __syncthreads();
  for (int s = 128; s > 0; s >>= 1) {
    if ((int)threadIdx.x < s) sm[threadIdx.x] = fmaxf(sm[threadIdx.x], sm[threadIdx.x + s]);
    __syncthreads();
  }
  if (threadIdx.x == 0) atomicMax((int*)(ws + OFF_SCAL + slotOut), __float_as_int(sm[0]));
}

// ---------------- power matvec: vout = P * (vin or ones) -------------------
template <int N>
__global__ __launch_bounds__(64) void k_mv(const float* __restrict__ P,
                                           const float* __restrict__ vin,
                                           float* __restrict__ vout, int useVec) {
  int i = blockIdx.x * 64 + threadIdx.x;
  const float4* Pr = (const float4*)(P + (size_t)i * N);
  float acc = 0.f;
  if (useVec) {
    const float4* v4 = (const float4*)vin;
    for (int j = 0; j < N / 4; ++j) {
      float4 a = Pr[j]; float4 b = v4[j];
      acc += a.x * b.x + a.y * b.y + a.z * b.z + a.w * b.w;
    }
  } else {
    for (int j = 0; j < N / 4; ++j) { float4 a = Pr[j]; acc += a.x + a.y + a.z + a.w; }
  }
  vout[i] = acc;
}

// ---------------- fp64 matrix-free Rayleigh pieces -------------------------
__global__ __launch_bounds__(128) void k_xtv(const float* __restrict__ x,
                                             const float* __restrict__ v,
                                             double* __restrict__ t) {
  int m = blockIdx.x * blockDim.x + threadIdx.x;  // 16 x 128 = 2048
  double acc = 0.0;
  for (int i = 0; i < D; ++i) acc += (double)x[(size_t)i * M + m] * (double)v[i];
  t[m] = acc;
}

__global__ __launch_bounds__(64) void k_xt(const float* __restrict__ x,
                                           const double* __restrict__ t,
                                           double* __restrict__ y) {
  int i = blockIdx.x * blockDim.x + threadIdx.x;  // 8 x 64 = 512
  double acc = 0.0;
  for (int m = 0; m < M; ++m) acc += (double)x[(size_t)i * M + m] * t[m];
  y[i] = acc;
}

__global__ __launch_bounds__(512) void k_tau(float* __restrict__ ws) {
  const double* y = (const double*)(ws + OFF_Y64);
  const float* v = ws + OFF_VV;
  __shared__ double sn[512], sd[512];
  int i = threadIdx.x;
  double vi = (double)v[i];
  sn[i] = vi * y[i];
  sd[i] = vi * vi;
  __syncthreads();
  for (int s = 256; s > 0; s >>= 1) {
    if (i < s) { sn[i] += sn[i + s]; sd[i] += sd[i + s]; }
    __syncthreads();
  }
  if (i == 0) {
    float max_sx = (float)(sn[0] / sd[0]);
    float eigD = ws[OFF_SCAL + SC_EIGD];
    float tau = 1.0f / (2.0f * (max_sx + LAM1 * eigD));
    float lam2 = (tau * LAM2C > 0.1f) ? 0.1f / tau : LAM2C;
    ws[OFF_SCAL + SC_TAU] = tau;
    ws[OFF_SCAL + SC_THR] = tau * lam2;
  }
}

__global__ __launch_bounds__(128) void k_eigd(float* __restrict__ ws) {
  int i = threadIdx.x;  // 128
  const float* DtD = ws + OFF_DTD;
  const float* v = ws + OFF_WD2;
  float acc = 0.f;
  for (int j = 0; j < L; ++j) acc += DtD[i * L + j] * v[j];
  __shared__ float sn[128], sd[128];
  sn[i] = acc * v[i]; sd[i] = v[i] * v[i];
  __syncthreads();
  for (int s = 64; s > 0; s >>= 1) {
    if (i < s) { sn[i] += sn[i + s]; sd[i] += sd[i + s]; }
    __syncthreads();
  }
  if (i == 0) ws[OFF_SCAL + SC_EIGD] = sn[0] / sd[0];
}

// ---------------- K1: conv check + A_new/B_new (speculative) ---------------
__global__ __launch_bounds__(256) void k_step1(const float* __restrict__ x,
                                               float* __restrict__ ws, int t) {
  int* iscal = (int*)(ws + OFF_SCAL);
  if (iscal[SI_DONE]) return;
  int bid = blockIdx.x, tid = threadIdx.x;

  if (bid == 0 && t >= 1) {  // convergence test for body t (uses ax^t vs ax^{t-1})
    __shared__ float snum[128], sden[128];
    if (tid < TAIL) {
      float s = 0.f;
#pragma unroll
      for (int slot = 0; slot < 16; ++slot) s += ws[OFF_PART + slot * 128 + tid];
      float ax = s / (float)(TAIL - tid);  // count = 2175 - k, k = 2048 + tid
      float yp = ws[OFF_YPREV + tid];
      float d = yp - ax;
      snum[tid] = d * d;
      sden[tid] = yp * yp;
      ws[OFF_YPREV + tid] = ax;
    }
    __syncthreads();
    if (tid == 0) {
      float num = 0.f, den = 0.f;
      for (int k = 0; k < TAIL; ++k) { num += snum[k]; den += sden[k]; }
      float conv = sqrtf(num) / sqrtf(den);
      if (conv <= EPSV) { iscal[SI_DONE] = 1; iscal[SI_PAR] = t & 1; }
    }
    __syncthreads();
  }

  // G2 = R @ x^T tile  (output 128x512, tiles 32x8, 256 blocks = 4x64)
  int rt = bid / 64, ct = bid % 64;
  int r = rt * 32 + tid / 8;
  int c = ct * 8 + tid % 8;
  const float4* Rr = (const float4*)(ws + OFF_R + (size_t)r * M);
  const float4* xr = (const float4*)(x + (size_t)c * M);
  float g2 = 0.f;
  for (int m4 = 0; m4 < M / 4; ++m4) {
    float4 a = Rr[m4], b = xr[m4];
    g2 += a.x * b.x + a.y * b.y + a.z * b.z + a.w * b.w;
  }
  // LAM1 * (DtD @ A)
  const float* A = ws + OFF_A + (t & 1) * (L * D);
  const float* DtD = ws + OFF_DTD;
  float gd = 0.f;
  const float4* Dr = (const float4*)(DtD + (size_t)r * L);
  for (int p4 = 0; p4 < L / 4; ++p4) {
    float4 dv = Dr[p4];
    gd += dv.x * A[(size_t)(p4 * 4 + 0) * D + c] + dv.y * A[(size_t)(p4 * 4 + 1) * D + c] +
          dv.z * A[(size_t)(p4 * 4 + 2) * D + c] + dv.w * A[(size_t)(p4 * 4 + 3) * D + c];
  }
  float tau = ws[OFF_SCAL + SC_TAU], thr = ws[OFF_SCAL + SC_THR];
  float ctv = ws[OFF_CTAB + t];
  float aold = A[(size_t)r * D + c];
  float bm = ws[OFF_BM + (t & 1) * (L * D) + (size_t)r * D + c];
  float z = bm - tau * (LAM1 * gd + g2);
  float az = fabsf(z) - thr;
  float anew = az > 0.f ? copysignf(az, z) : 0.f;
  float bnew = aold + ctv * (anew - aold);
  ws[OFF_A + ((t + 1) & 1) * (L * D) + (size_t)r * D + c] = anew;
  ws[OFF_BM + ((t + 1) & 1) * (L * D) + (size_t)r * D + c] = bnew;
}

// ---------------- K2: Ax = A_new @ x, R, hankel-tail partials --------------
__global__ __launch_bounds__(256) void k_step2(const float* __restrict__ x,
                                               const float* __restrict__ part_y,
                                               const float* __restrict__ mask,
                                               float* __restrict__ ws, int t) {
  int* iscal = (int*)(ws + OFF_SCAL);
  if (iscal[SI_DONE]) return;
  int bid = blockIdx.x, tid = threadIdx.x;
  int rt = bid / 32, ct = bid % 32;  // 8 x 32 blocks, tile 16 rows x 64 cols
  int r0 = rt * 16, c0 = ct * 64;
  int lane = tid % 64, w = tid / 64;  // wave w owns rows r0+4w .. r0+4w+3
  const float* A = ws + OFF_A + ((t + 1) & 1) * (L * D);
  int c = c0 + lane;
  float acc[4] = {0.f, 0.f, 0.f, 0.f};
  for (int d4 = 0; d4 < D / 4; ++d4) {
    float xs0 = x[(size_t)(d4 * 4 + 0) * M + c];
    float xs1 = x[(size_t)(d4 * 4 + 1) * M + c];
    float xs2 = x[(size_t)(d4 * 4 + 2) * M + c];
    float xs3 = x[(size_t)(d4 * 4 + 3) * M + c];
#pragma unroll
    for (int k = 0; k < 4; ++k) {
      float4 av = ((const float4*)(A + (size_t)(r0 + 4 * w + k) * D))[d4];
      acc[k] += av.x * xs0 + av.y * xs1 + av.z * xs2 + av.w * xs3;
    }
  }
  __shared__ float tile[16][65];
#pragma unroll
  for (int k = 0; k < 4; ++k) {
    int r = r0 + 4 * w + k;
    size_t o = (size_t)r * M + c;
    ws[OFF_AX + o] = acc[k];
    ws[OFF_R + o] = mask[o] * (acc[k] - part_y[o]);
    tile[4 * w + k][lane] = acc[k];
  }
  if (ct >= 30) {  // deterministic hankel-tail partial sums (k = i+j >= 2048)
    __syncthreads();
    int slot = rt * 2 + (ct - 30);
    if (tid < TAIL) {
      int k = M + tid;  // 2048 + tid
      int rlo = max(r0, k - (c0 + 63));
      int rhi = min(r0 + 15, k - c0);
      float s = 0.f;
      for (int r = rlo; r <= rhi; ++r) s += tile[r - r0][(k - r) - c0];
      ws[OFF_PART + slot * 128 + tid] = s;
    }
  }
}

// ---------------- final copy to d_out --------------------------------------
__global__ __launch_bounds__(256) void k_final(const float* __restrict__ ws,
                                               float* __restrict__ out) {
  const int* iscal = (const int*)(ws + OFF_SCAL);
  int par = iscal[SI_PAR];
  int gid = blockIdx.x * blockDim.x + threadIdx.x;
  int stride = gridDim.x * blockDim.x;
  for (int i = gid; i < L * M; i += stride) out[i] = ws[OFF_AX + i];
  for (int i = gid; i < L * D; i += stride) out[L * M + i] = ws[OFF_A + par * (L * D) + i];
}

// ---------------------------------------------------------------------------
extern "C" void kernel_launch(void* const* d_in, const int* in_sizes, int n_in,
                              void* d_out, int out_size, void* d_ws, size_t ws_size,
                              hipStream_t stream) {
  (void)in_sizes; (void)n_in; (void)out_size; (void)ws_size;
  const float* x = (const float*)d_in[0];
  const float* py = (const float*)d_in[1];
  const float* mk = (const float*)d_in[2];
  const float* y0 = (const float*)d_in[3];
  float* out = (float*)d_out;
  float* ws = (float*)d_ws;

  float* gP = ws + OFF_P;
  float* gQ = ws + OFF_Q;
  float* dP = ws + OFF_DP;
  float* dQ = ws + OFF_DQ;
  float* gDtD = ws + OFF_DTD;

  k_init<<<256, 256, 0, stream>>>(ws, py, mk, y0);

  // --- max eigenvalue of x x^T ---
  k_xxt<<<256, 256, 0, stream>>>(x, ws);
  for (int s = 0; s < 16; ++s) {
    const float* src = (s % 2 == 0) ? gP : gQ;
    float* dst = (s % 2 == 0) ? gQ : gP;
    k_sq<512, 16><<<256, 256, 0, stream>>>(src, dst, ws, SC_MX + s, SC_MX + s + 1);
  }  // final matrix in gP
  k_mv<512><<<8, 64, 0, stream>>>(gP, nullptr, ws + OFF_WV, 0);
  k_mv<512><<<8, 64, 0, stream>>>(gP, ws + OFF_WV, ws + OFF_VV, 1);
  k_mv<512><<<8, 64, 0, stream>>>(gP, ws + OFF_VV, ws + OFF_WV, 1);
  k_mv<512><<<8, 64, 0, stream>>>(gP, ws + OFF_WV, ws + OFF_VV, 1);
  k_xtv<<<16, 128, 0, stream>>>(x, ws + OFF_VV, (double*)(ws + OFF_T64));
  k_xt<<<8, 64, 0, stream>>>(x, (const double*)(ws + OFF_T64), (double*)(ws + OFF_Y64));

  // --- max eigenvalue of Delta^T Delta ---
  for (int s = 0; s < 14; ++s) {
    const float* src = (s == 0) ? gDtD : ((s % 2 == 1) ? dP : dQ);
    float* dst = (s % 2 == 0) ? dP : dQ;
    k_sq<128, 4><<<16, 256, 0, stream>>>(src, dst, ws, SC_MXD + s, SC_MXD + s + 1);
  }  // final in dQ
  k_mv<128><<<2, 64, 0, stream>>>(dQ, nullptr, ws + OFF_WD, 0);
  k_mv<128><<<2, 64, 0, stream>>>(dQ, ws + OFF_WD, ws + OFF_WD2, 2);  // no scale needed
  k_eigd<<<1, 128, 0, stream>>>(ws);

  // tau, thr (needs eigD + fp64 Rayleigh pieces)
  k_tau<<<1, 512, 0, stream>>>(ws);

  // --- main FISTA loop (device-side early exit via done flag) ---
  for (int t = 0; t < MAXIT; ++t) {
    k_step1<<<256, 256, 0, stream>>>(x, ws, t);
    k_step2<<<256, 256, 0, stream>>>(x, py, mk, ws, t);
  }

  k_final<<<256, 256, 0, stream>>>(ws, out);
}

// Round 2
// 12377.586 us; speedup vs baseline: 1.7610x; 1.7610x over previous
//
#include <hip/hip_runtime.h>
#include <math.h>

// ---------------------------------------------------------------------------
// FISTA sparse solver, L=128, D=512, M=2048, MAX_ITER=200, EPS=1e-5.
// R2: occupancy-focused restructure of the main loop.
//  - k1p: split-K (8 chunks) partial G2 = R@x^T; chunk 7 folds LAM1*(DtD@A)
//    and the convergence check. 512 blocks -> 2 waves/SIMD (was 1).
//  - k1b: combine partials + soft-threshold prox + momentum B update.
//  - k2:  A_new@x with d-contraction split across two 256-thread halves of a
//    512-thread block (LDS combine) -> 2 waves/SIMD; fuses R, Ax store, and
//    hankel-tail partial sums.
//  - Device-side done flag preserves the reference's early exit inside the
//    captured graph; all reductions fixed-order (replay-deterministic).
// ---------------------------------------------------------------------------

#define L 128
#define D 512
#define M 2048
#define TAIL (L - 1)     // 127
#define MAXIT 200
#define EPSV 1e-5f
#define LAM1 0.1f
#define LAM2C 0.1f
#define LD (L * D)       // 65536

// workspace offsets (in floats)
#define OFF_A     0           // 2 x LD
#define OFF_BM    131072      // 2 x LD
#define OFF_R     262144      // L*M
#define OFF_AX    524288      // L*M
#define OFF_P     786432      // 512x512 (setup); re-used as k1 partials (8 x LD)
#define OFF_PAR   OFF_P
#define OFF_Q     1048576     // 512x512 (setup)
#define OFF_DTD   1310720     // 128x128 (persistent)
#define OFF_DP    1327104     // 128x128
#define OFF_DQ    1343488     // 128x128
#define OFF_CTAB  1359872     // 256
#define OFF_YPREV 1360128     // 128
#define OFF_PART  1360256     // 16 x 128
#define OFF_WV    1362304     // 512
#define OFF_VV    1362816     // 512
#define OFF_T64   1363328     // 2048 doubles
#define OFF_Y64   1367424     // 512 doubles
#define OFF_SCAL  1368448     // 64
#define OFF_WD    1368512     // 128
#define OFF_WD2   1368640     // 128

#define SC_MX    0    // squaring maxima (x chain), 0..12
#define SC_MXD   24   // squaring maxima (delta chain), 24..34
#define SC_EIGD  44
#define SC_TAU   45
#define SC_THR   46
#define SI_DONE  48
#define SI_PAR   49

__device__ __forceinline__ float delta_elem(int i, int j) {
  if (i == 0) return 0.f;
  if (i == 1) return (j == 0) ? -1.f : (j == 1 ? 1.f : 0.f);
  return (j == i) ? 1.f : (j == i - 1 ? -2.f : (j == i - 2 ? 1.f : 0.f));
}

// ---------------- init ------------------------------------------------------
__global__ __launch_bounds__(256) void k_init(float* __restrict__ ws,
                                              const float* __restrict__ part_y,
                                              const float* __restrict__ mask,
                                              const float* __restrict__ y0) {
  int gid = blockIdx.x * blockDim.x + threadIdx.x;
  int stride = gridDim.x * blockDim.x;
  for (int i = gid; i < 4 * LD; i += stride) ws[OFF_A + i] = 0.f;
  for (int i = gid; i < L * M; i += stride) ws[OFF_R + i] = -mask[i] * part_y[i];
  for (int i = gid; i < L * L; i += stride) {
    int r = i / L, c = i % L;
    float s = 0.f;
    for (int k = 0; k < L; ++k) s += delta_elem(k, r) * delta_elem(k, c);
    ws[OFF_DTD + i] = s;
  }
  if (gid < TAIL) ws[OFF_YPREV + gid] = y0[M + gid];
  if (gid == 0) {
    for (int i = 0; i < 64; ++i) ws[OFF_SCAL + i] = 0.f;
    ws[OFF_SCAL + SC_MXD] = 6.0f;  // exact max|DtD|
    float a = 1.f;
    for (int t = 0; t < MAXIT; ++t) {
      float an = (1.f + sqrtf(1.f + 4.f * a * a)) * 0.5f;
      ws[OFF_CTAB + t] = (a - 1.f) / an;
      a = an;
    }
  }
}

// ---------------- B = x x^T (512x512), track max|entry| --------------------
__global__ __launch_bounds__(256) void k_xxt(const float* __restrict__ x,
                                             float* __restrict__ ws) {
  int bt = blockIdx.x;
  int r0 = (bt / 16) * 32, c0 = (bt % 16) * 32;
  int rr = threadIdx.x / 32, cl = threadIdx.x % 32;
  int c = c0 + cl;
  const float4* xc = (const float4*)(x + (size_t)c * M);
  float acc[4] = {0.f, 0.f, 0.f, 0.f};
  for (int m4 = 0; m4 < M / 4; ++m4) {
    float4 b = xc[m4];
#pragma unroll
    for (int k = 0; k < 4; ++k) {
      float4 a = ((const float4*)(x + (size_t)(r0 + rr + 8 * k) * M))[m4];
      acc[k] += a.x * b.x + a.y * b.y + a.z * b.z + a.w * b.w;
    }
  }
  float* P = ws + OFF_P;
  float mloc = 0.f;
#pragma unroll
  for (int k = 0; k < 4; ++k) {
    P[(size_t)(r0 + rr + 8 * k) * D + c] = acc[k];
    mloc = fmaxf(mloc, fabsf(acc[k]));
  }
  __shared__ float sm[256];
  sm[threadIdx.x] = mloc; __syncthreads();
  for (int s = 128; s > 0; s >>= 1) {
    if ((int)threadIdx.x < s) sm[threadIdx.x] = fmaxf(sm[threadIdx.x], sm[threadIdx.x + s]);
    __syncthreads();
  }
  if (threadIdx.x == 0) atomicMax((int*)(ws + OFF_SCAL + SC_MX), __float_as_int(sm[0]));
}

// ---------------- symmetric matrix squaring: dst = (src/m)^2 ---------------
template <int N, int TILES>
__global__ __launch_bounds__(256) void k_sq(const float* __restrict__ src,
                                            float* __restrict__ dst,
                                            float* __restrict__ ws,
                                            int slotIn, int slotOut) {
  float sc = 1.0f / ws[OFF_SCAL + slotIn];
  int bt = blockIdx.x;
  int r0 = (bt / TILES) * 32, c0 = (bt % TILES) * 32;
  int rr = threadIdx.x / 32, cl = threadIdx.x % 32;
  int c = c0 + cl;
  const float4* bc = (const float4*)(src + (size_t)c * N);
  float acc[4] = {0.f, 0.f, 0.f, 0.f};
  for (int m4 = 0; m4 < N / 4; ++m4) {
    float4 b = bc[m4];
#pragma unroll
    for (int k = 0; k < 4; ++k) {
      float4 a = ((const float4*)(src + (size_t)(r0 + rr + 8 * k) * N))[m4];
      acc[k] += a.x * b.x + a.y * b.y + a.z * b.z + a.w * b.w;
    }
  }
  float mloc = 0.f;
#pragma unroll
  for (int k = 0; k < 4; ++k) {
    float v = acc[k] * sc * sc;
    dst[(size_t)(r0 + rr + 8 * k) * N + c] = v;
    mloc = fmaxf(mloc, fabsf(v));
  }
  __shared__ float sm[256];
  sm[threadIdx.x] = mloc; __syncthreads();
  for (int s = 128; s > 0; s >>= 1) {
    if ((int)threadIdx.x < s) sm[threadIdx.x] = fmaxf(sm[threadIdx.x], sm[threadIdx.x + s]);
    __syncthreads();
  }
  if (threadIdx.x == 0) atomicMax((int*)(ws + OFF_SCAL + slotOut), __float_as_int(sm[0]));
}

// ---------------- power matvec ---------------------------------------------
template <int N>
__global__ __launch_bounds__(64) void k_mv(const float* __restrict__ P,
                                           const float* __restrict__ vin,
                                           float* __restrict__ vout, int useVec) {
  int i = blockIdx.x * 64 + threadIdx.x;
  const float4* Pr = (const float4*)(P + (size_t)i * N);
  float acc = 0.f;
  if (useVec) {
    const float4* v4 = (const float4*)vin;
    for (int j = 0; j < N / 4; ++j) {
      float4 a = Pr[j]; float4 b = v4[j];
      acc += a.x * b.x + a.y * b.y + a.z * b.z + a.w * b.w;
    }
  } else {
    for (int j = 0; j < N / 4; ++j) { float4 a = Pr[j]; acc += a.x + a.y + a.z + a.w; }
  }
  vout[i] = acc;
}

// ---------------- fp64 matrix-free Rayleigh pieces -------------------------
__global__ __launch_bounds__(128) void k_xtv(const float* __restrict__ x,
                                             const float* __restrict__ v,
                                             double* __restrict__ t) {
  int m = blockIdx.x * blockDim.x + threadIdx.x;
  double acc = 0.0;
  for (int i = 0; i < D; ++i) acc += (double)x[(size_t)i * M + m] * (double)v[i];
  t[m] = acc;
}

__global__ __launch_bounds__(64) void k_xt(const float* __restrict__ x,
                                           const double* __restrict__ t,
                                           double* __restrict__ y) {
  int i = blockIdx.x * blockDim.x + threadIdx.x;
  double acc = 0.0;
  for (int m = 0; m < M; ++m) acc += (double)x[(size_t)i * M + m] * t[m];
  y[i] = acc;
}

__global__ __launch_bounds__(512) void k_tau(float* __restrict__ ws) {
  const double* y = (const double*)(ws + OFF_Y64);
  const float* v = ws + OFF_VV;
  __shared__ double sn[512], sd[512];
  int i = threadIdx.x;
  double vi = (double)v[i];
  sn[i] = vi * y[i];
  sd[i] = vi * vi;
  __syncthreads();
  for (int s = 256; s > 0; s >>= 1) {
    if (i < s) { sn[i] += sn[i + s]; sd[i] += sd[i + s]; }
    __syncthreads();
  }
  if (i == 0) {
    float max_sx = (float)(sn[0] / sd[0]);
    float eigD = ws[OFF_SCAL + SC_EIGD];
    float tau = 1.0f / (2.0f * (max_sx + LAM1 * eigD));
    float lam2 = (tau * LAM2C > 0.1f) ? 0.1f / tau : LAM2C;
    ws[OFF_SCAL + SC_TAU] = tau;
    ws[OFF_SCAL + SC_THR] = tau * lam2;
  }
}

__global__ __launch_bounds__(128) void k_eigd(float* __restrict__ ws) {
  int i = threadIdx.x;
  const float* DtD = ws + OFF_DTD;
  const float* v = ws + OFF_WD2;
  float acc = 0.f;
  for (int j = 0; j < L; ++j) acc += DtD[i * L + j] * v[j];
  __shared__ float sn[128], sd[128];
  sn[i] = acc * v[i]; sd[i] = v[i] * v[i];
  __syncthreads();
  for (int s = 64; s > 0; s >>= 1) {
    if (i < s) { sn[i] += sn[i + s]; sd[i] += sd[i + s]; }
    __syncthreads();
  }
  if (i == 0) ws[OFF_SCAL + SC_EIGD] = sn[0] / sd[0];
}

// ---------------- k1p: split-K partial G2 (+gd on chunk 7, +conv check) ----
// grid 512 = 8 chunks x 64 tiles (8 rt x 8 ct, tile 16 rows x 64 cols)
__global__ __launch_bounds__(256) void k1p(const float* __restrict__ x,
                                           float* __restrict__ ws, int t) {
  int* iscal = (int*)(ws + OFF_SCAL);
  if (iscal[SI_DONE]) return;
  int chunk = blockIdx.x >> 6;
  int tile = blockIdx.x & 63;
  int rt = tile >> 3, ct = tile & 7;
  int tid = threadIdx.x;
  int w = tid >> 6, lane = tid & 63;
  int r0 = rt * 16 + w * 4;
  int c = ct * 64 + lane;

  if (chunk == 7 && tile == 0 && t >= 1) {
    __shared__ float snum[128], sden[128];
    if (tid < TAIL) {
      float s = 0.f;
#pragma unroll
      for (int slot = 0; slot < 16; ++slot) s += ws[OFF_PART + slot * 128 + tid];
      float ax = s / (float)(TAIL - tid);
      float yp = ws[OFF_YPREV + tid];
      float d = yp - ax;
      snum[tid] = d * d;
      sden[tid] = yp * yp;
      ws[OFF_YPREV + tid] = ax;
    }
    __syncthreads();
    if (tid == 0) {
      float num = 0.f, den = 0.f;
      for (int k = 0; k < TAIL; ++k) { num += snum[k]; den += sden[k]; }
      float conv = sqrtf(num) / sqrtf(den);
      if (conv <= EPSV) { iscal[SI_DONE] = 1; iscal[SI_PAR] = t & 1; }
    }
  }

  float acc0 = 0.f, acc1 = 0.f, acc2 = 0.f, acc3 = 0.f;
  {
    const float4* xr = (const float4*)(x + (size_t)c * M) + chunk * 64;
    const float4* R0 = (const float4*)(ws + OFF_R + (size_t)(r0 + 0) * M) + chunk * 64;
    const float4* R1 = (const float4*)(ws + OFF_R + (size_t)(r0 + 1) * M) + chunk * 64;
    const float4* R2 = (const float4*)(ws + OFF_R + (size_t)(r0 + 2) * M) + chunk * 64;
    const float4* R3 = (const float4*)(ws + OFF_R + (size_t)(r0 + 3) * M) + chunk * 64;
#pragma unroll 4
    for (int i = 0; i < 64; ++i) {
      float4 b = xr[i];
      float4 a0 = R0[i], a1 = R1[i], a2 = R2[i], a3 = R3[i];
      acc0 += a0.x * b.x + a0.y * b.y + a0.z * b.z + a0.w * b.w;
      acc1 += a1.x * b.x + a1.y * b.y + a1.z * b.z + a1.w * b.w;
      acc2 += a2.x * b.x + a2.y * b.y + a2.z * b.z + a2.w * b.w;
      acc3 += a3.x * b.x + a3.y * b.y + a3.z * b.z + a3.w * b.w;
    }
  }
  if (chunk == 7) {  // fold LAM1 * (DtD @ A_t)
    const float4* D0 = (const float4*)(ws + OFF_DTD + (size_t)(r0 + 0) * L);
    const float4* D1 = (const float4*)(ws + OFF_DTD + (size_t)(r0 + 1) * L);
    const float4* D2 = (const float4*)(ws + OFF_DTD + (size_t)(r0 + 2) * L);
    const float4* D3 = (const float4*)(ws + OFF_DTD + (size_t)(r0 + 3) * L);
    const float* Ab = ws + OFF_A + (size_t)(t & 1) * LD;
    float g0 = 0.f, g1 = 0.f, g2 = 0.f, g3 = 0.f;
#pragma unroll 2
    for (int p4 = 0; p4 < 32; ++p4) {
      float4 d0 = D0[p4], d1 = D1[p4], d2 = D2[p4], d3 = D3[p4];
      float ap0 = Ab[(size_t)(p4 * 4 + 0) * D + c];
      float ap1 = Ab[(size_t)(p4 * 4 + 1) * D + c];
      float ap2 = Ab[(size_t)(p4 * 4 + 2) * D + c];
      float ap3 = Ab[(size_t)(p4 * 4 + 3) * D + c];
      g0 += d0.x * ap0 + d0.y * ap1 + d0.z * ap2 + d0.w * ap3;
      g1 += d1.x * ap0 + d1.y * ap1 + d1.z * ap2 + d1.w * ap3;
      g2 += d2.x * ap0 + d2.y * ap1 + d2.z * ap2 + d2.w * ap3;
      g3 += d3.x * ap0 + d3.y * ap1 + d3.z * ap2 + d3.w * ap3;
    }
    acc0 += LAM1 * g0; acc1 += LAM1 * g1; acc2 += LAM1 * g2; acc3 += LAM1 * g3;
  }
  float* P = ws + OFF_PAR + (size_t)chunk * LD;
  P[(size_t)(r0 + 0) * D + c] = acc0;
  P[(size_t)(r0 + 1) * D + c] = acc1;
  P[(size_t)(r0 + 2) * D + c] = acc2;
  P[(size_t)(r0 + 3) * D + c] = acc3;
}

// ---------------- k1b: combine + prox + momentum ---------------------------
__global__ __launch_bounds__(256) void k1b(float* __restrict__ ws, int t) {
  int* iscal = (int*)(ws + OFF_SCAL);
  if (iscal[SI_DONE]) return;
  int idx = blockIdx.x * 256 + threadIdx.x;  // 65536 threads
  float g = 0.f;
#pragma unroll
  for (int ch = 0; ch < 8; ++ch) g += ws[OFF_PAR + ch * LD + idx];
  float tau = ws[OFF_SCAL + SC_TAU];
  float thr = ws[OFF_SCAL + SC_THR];
  float ctv = ws[OFF_CTAB + t];
  float aold = ws[OFF_A + (t & 1) * LD + idx];
  float bm = ws[OFF_BM + (t & 1) * LD + idx];
  float z = bm - tau * g;
  float az = fabsf(z) - thr;
  float anew = az > 0.f ? copysignf(az, z) : 0.f;
  ws[OFF_A + ((t + 1) & 1) * LD + idx] = anew;
  ws[OFF_BM + ((t + 1) & 1) * LD + idx] = aold + ctv * (anew - aold);
}

// ---------------- k2: Ax = A_new@x, R, hankel partials ---------------------
// grid 256 (8 rt x 32 ct), block 512: two 256-thread halves split d
__global__ __launch_bounds__(512) void k2(const float* __restrict__ x,
                                          const float* __restrict__ py,
                                          const float* __restrict__ mask,
                                          float* __restrict__ ws, int t) {
  int* iscal = (int*)(ws + OFF_SCAL);
  if (iscal[SI_DONE]) return;
  int bid = blockIdx.x;
  int rt = bid >> 5, ct = bid & 31;
  int tid = threadIdx.x;
  int half = tid >> 8;
  int w2 = (tid >> 6) & 3;
  int lane = tid & 63;
  int r0 = rt * 16 + w2 * 4;
  int c = ct * 64 + lane;
  const float* A = ws + OFF_A + (size_t)((t + 1) & 1) * LD;
  float acc0 = 0.f, acc1 = 0.f, acc2 = 0.f, acc3 = 0.f;
  int d4lo = half * 64;
#pragma unroll 2
  for (int d4 = d4lo; d4 < d4lo + 64; ++d4) {
    float xs0 = x[(size_t)(d4 * 4 + 0) * M + c];
    float xs1 = x[(size_t)(d4 * 4 + 1) * M + c];
    float xs2 = x[(size_t)(d4 * 4 + 2) * M + c];
    float xs3 = x[(size_t)(d4 * 4 + 3) * M + c];
    float4 a0 = ((const float4*)(A + (size_t)(r0 + 0) * D))[d4];
    float4 a1 = ((const float4*)(A + (size_t)(r0 + 1) * D))[d4];
    float4 a2 = ((const float4*)(A + (size_t)(r0 + 2) * D))[d4];
    float4 a3 = ((const float4*)(A + (size_t)(r0 + 3) * D))[d4];
    acc0 += a0.x * xs0 + a0.y * xs1 + a0.z * xs2 + a0.w * xs3;
    acc1 += a1.x * xs0 + a1.y * xs1 + a1.z * xs2 + a1.w * xs3;
    acc2 += a2.x * xs0 + a2.y * xs1 + a2.z * xs2 + a2.w * xs3;
    acc3 += a3.x * xs0 + a3.y * xs1 + a3.z * xs2 + a3.w * xs3;
  }
  __shared__ float tile[16][65];
  if (half == 0) {
    tile[w2 * 4 + 0][lane] = acc0;
    tile[w2 * 4 + 1][lane] = acc1;
    tile[w2 * 4 + 2][lane] = acc2;
    tile[w2 * 4 + 3][lane] = acc3;
  }
  __syncthreads();
  if (half == 1) {
    float s0 = tile[w2 * 4 + 0][lane] + acc0;
    float s1 = tile[w2 * 4 + 1][lane] + acc1;
    float s2 = tile[w2 * 4 + 2][lane] + acc2;
    float s3 = tile[w2 * 4 + 3][lane] + acc3;
    size_t o0 = (size_t)(r0 + 0) * M + c;
    size_t o1 = (size_t)(r0 + 1) * M + c;
    size_t o2 = (size_t)(r0 + 2) * M + c;
    size_t o3 = (size_t)(r0 + 3) * M + c;
    ws[OFF_AX + o0] = s0; ws[OFF_R + o0] = mask[o0] * (s0 - py[o0]);
    ws[OFF_AX + o1] = s1; ws[OFF_R + o1] = mask[o1] * (s1 - py[o1]);
    ws[OFF_AX + o2] = s2; ws[OFF_R + o2] = mask[o2] * (s2 - py[o2]);
    ws[OFF_AX + o3] = s3; ws[OFF_R + o3] = mask[o3] * (s3 - py[o3]);
    tile[w2 * 4 + 0][lane] = s0;
    tile[w2 * 4 + 1][lane] = s1;
    tile[w2 * 4 + 2][lane] = s2;
    tile[w2 * 4 + 3][lane] = s3;
  }
  if (ct >= 30) {  // hankel-tail partial sums (diag k = 2048+tid)
    __syncthreads();
    int slot = rt * 2 + (ct - 30);
    if (tid < TAIL) {
      int kk = M + tid;
      int rbase = rt * 16, c0 = ct * 64;
      int rlo = max(rbase, kk - (c0 + 63));
      int rhi = min(rbase + 15, kk - c0);
      float s = 0.f;
      for (int r = rlo; r <= rhi; ++r) s += tile[r - rbase][(kk - r) - c0];
      ws[OFF_PART + slot * 128 + tid] = s;
    }
  }
}

// ---------------- final copy to d_out --------------------------------------
__global__ __launch_bounds__(256) void k_final(const float* __restrict__ ws,
                                               float* __restrict__ out) {
  const int* iscal = (const int*)(ws + OFF_SCAL);
  int par = iscal[SI_PAR];
  int gid = blockIdx.x * blockDim.x + threadIdx.x;
  int stride = gridDim.x * blockDim.x;
  for (int i = gid; i < L * M; i += stride) out[i] = ws[OFF_AX + i];
  for (int i = gid; i < LD; i += stride) out[L * M + i] = ws[OFF_A + par * LD + i];
}

// ---------------------------------------------------------------------------
extern "C" void kernel_launch(void* const* d_in, const int* in_sizes, int n_in,
                              void* d_out, int out_size, void* d_ws, size_t ws_size,
                              hipStream_t stream) {
  (void)in_sizes; (void)n_in; (void)out_size; (void)ws_size;
  const float* x = (const float*)d_in[0];
  const float* py = (const float*)d_in[1];
  const float* mk = (const float*)d_in[2];
  const float* y0 = (const float*)d_in[3];
  float* out = (float*)d_out;
  float* ws = (float*)d_ws;

  float* gP = ws + OFF_P;
  float* gQ = ws + OFF_Q;
  float* dP = ws + OFF_DP;
  float* dQ = ws + OFF_DQ;
  float* gDtD = ws + OFF_DTD;

  k_init<<<256, 256, 0, stream>>>(ws, py, mk, y0);

  // --- max eigenvalue of x x^T: 12 normalized squarings + power + Rayleigh ---
  k_xxt<<<256, 256, 0, stream>>>(x, ws);
  for (int s = 0; s < 12; ++s) {
    const float* src = (s % 2 == 0) ? gP : gQ;
    float* dst = (s % 2 == 0) ? gQ : gP;
    k_sq<512, 16><<<256, 256, 0, stream>>>(src, dst, ws, SC_MX + s, SC_MX + s + 1);
  }  // final matrix in gP
  k_mv<512><<<8, 64, 0, stream>>>(gP, nullptr, ws + OFF_WV, 0);
  k_mv<512><<<8, 64, 0, stream>>>(gP, ws + OFF_WV, ws + OFF_VV, 1);
  k_mv<512><<<8, 64, 0, stream>>>(gP, ws + OFF_VV, ws + OFF_WV, 1);
  k_mv<512><<<8, 64, 0, stream>>>(gP, ws + OFF_WV, ws + OFF_VV, 1);
  k_xtv<<<16, 128, 0, stream>>>(x, ws + OFF_VV, (double*)(ws + OFF_T64));
  k_xt<<<8, 64, 0, stream>>>(x, (const double*)(ws + OFF_T64), (double*)(ws + OFF_Y64));

  // --- max eigenvalue of Delta^T Delta: 10 squarings + power ---
  for (int s = 0; s < 10; ++s) {
    const float* src = (s == 0) ? gDtD : ((s % 2 == 1) ? dP : dQ);
    float* dst = (s % 2 == 0) ? dP : dQ;
    k_sq<128, 4><<<16, 256, 0, stream>>>(src, dst, ws, SC_MXD + s, SC_MXD + s + 1);
  }  // final in dQ
  k_mv<128><<<2, 64, 0, stream>>>(dQ, nullptr, ws + OFF_WD, 0);
  k_mv<128><<<2, 64, 0, stream>>>(dQ, ws + OFF_WD, ws + OFF_WD2, 2);
  k_eigd<<<1, 128, 0, stream>>>(ws);
  k_tau<<<1, 512, 0, stream>>>(ws);

  // --- main FISTA loop (device-side early exit via done flag) ---
  for (int t = 0; t < MAXIT; ++t) {
    k1p<<<512, 256, 0, stream>>>(x, ws, t);
    k1b<<<256, 256, 0, stream>>>(ws, t);
    k2<<<256, 512, 0, stream>>>(x, py, mk, ws, t);
  }

  k_final<<<256, 256, 0, stream>>>(ws, out);
}